// Round 1
// baseline (329.666 us; speedup 1.0000x reference)
//
#include <hip/hip_runtime.h>

#define NCELLS 32768      // 256*128*1
#define MAXV   12000
#define MAXP   100
#define KCAP   128
#define FINF   0x7F7F7F7F // > any point index, works as +inf for atomicMin

// meta slots
#define M_NSEL   0
#define M_CUTOFF 1
#define M_BSTAR  2
#define M_BASE   3
#define M_NEED   4
#define M_NCAND  5
#define M_VOXNUM 6

__device__ __forceinline__ int point_key(float px, float py, float pz, bool& valid) {
    // exact IEEE f32 match to reference: floor((x - lo)/vs), lo=(0,-10.24,-3), vs=(0.16,0.16,4)
    float fx = floorf((px - 0.0f)    / 0.16f);
    float fy = floorf((py + 10.24f)  / 0.16f);
    float fz = floorf((pz + 3.0f)    / 4.0f);
    valid = (fx >= 0.0f) && (fx < 256.0f) &&
            (fy >= 0.0f) && (fy < 128.0f) &&
            (fz >= 0.0f) && (fz < 1.0f);
    if (!valid) return 0;
    int cx = (int)fx, cy = (int)fy, cz = (int)fz;
    return (cz * 128 + cy) * 256 + cx;
}

__global__ void k_points(const float4* __restrict__ x, int n, int* __restrict__ first) {
    int i = blockIdx.x * blockDim.x + threadIdx.x;
    if (i >= n) return;
    float4 p = x[i];
    bool valid; int key = point_key(p.x, p.y, p.z, valid);
    if (valid) atomicMin(&first[key], i);
}

__global__ void k_hist(const int* __restrict__ first, int* __restrict__ hist) {
    int k = blockIdx.x * blockDim.x + threadIdx.x;
    if (k >= NCELLS) return;
    int f = first[k];
    if (f != FINF) atomicAdd(&hist[f >> 11], 1);   // buckets of 2048 indices
}

__global__ void k_select(const int* __restrict__ hist, int* __restrict__ meta, int n) {
    __shared__ int s[1024];
    int t = threadIdx.x;
    int v = hist[t];
    s[t] = v;
    __syncthreads();
    for (int d = 1; d < 1024; d <<= 1) {           // inclusive Hillis-Steele scan
        int add = (t >= d) ? s[t - d] : 0;
        __syncthreads();
        s[t] += add;
        __syncthreads();
    }
    int total = s[1023];
    int incl  = s[t];
    int excl  = incl - v;
    if (t == 0) {
        if (total <= MAXV) { meta[M_CUTOFF] = n; meta[M_VOXNUM] = total; meta[M_NEED] = 0; }
        else               { meta[M_VOXNUM] = MAXV; meta[M_NEED] = 1; }
    }
    // 0-based target rank = MAXV (the 12001st smallest first)
    if (total > MAXV && excl <= MAXV && incl > MAXV) {
        meta[M_BSTAR] = t;
        meta[M_BASE]  = excl;
    }
}

__global__ void k_cand(const int* __restrict__ first, int* __restrict__ meta, int* __restrict__ cand) {
    if (meta[M_NEED] == 0) return;
    int k = blockIdx.x * blockDim.x + threadIdx.x;
    if (k >= NCELLS) return;
    int f = first[k];
    if (f != FINF && (f >> 11) == meta[M_BSTAR]) {
        int pos = atomicAdd(&meta[M_NCAND], 1);
        cand[pos] = f;                              // <= 2048 distinct values per bucket
    }
}

__global__ void k_cut(const int* __restrict__ cand, int* __restrict__ meta) {
    if (meta[M_NEED] == 0) return;
    __shared__ int sc[2048];
    int nc = meta[M_NCAND];
    int target = MAXV - meta[M_BASE];
    for (int j = threadIdx.x; j < nc; j += blockDim.x) sc[j] = cand[j];
    __syncthreads();
    for (int j = threadIdx.x; j < nc; j += blockDim.x) {
        int e = sc[j];
        int cnt = 0;
        for (int q = 0; q < nc; ++q) cnt += (sc[q] < e);
        if (cnt == target) meta[M_CUTOFF] = e;      // unique (values distinct)
    }
}

__global__ void k_collect(const int* __restrict__ first, int* __restrict__ meta,
                          int* __restrict__ selF, int* __restrict__ selK) {
    int k = blockIdx.x * blockDim.x + threadIdx.x;
    if (k >= NCELLS) return;
    int cutoff = meta[M_CUTOFF];
    int f = first[k];
    if (f < cutoff) {                               // FINF > n >= cutoff, excludes empty cells
        int pos = atomicAdd(&meta[M_NSEL], 1);
        selF[pos] = f;
        selK[pos] = k;
    }
}

__global__ void k_rank(const int* __restrict__ selF, const int* __restrict__ selK,
                       const int* __restrict__ meta, int* __restrict__ cellvox,
                       float* __restrict__ out_coors) {
    int nsel = meta[M_NSEL];
    int i = blockIdx.x * blockDim.x + threadIdx.x;
    int myF = (i < nsel) ? selF[i] : 0x7FFFFFFF;
    int rank = 0;
    __shared__ int sf[256];
    for (int base = 0; base < nsel; base += 256) {
        int j = base + (int)threadIdx.x;
        sf[threadIdx.x] = (j < nsel) ? selF[j] : 0x7FFFFFFF;
        __syncthreads();
        int lim = min(256, nsel - base);
        for (int t = 0; t < lim; ++t) rank += (sf[t] < myF);
        __syncthreads();
    }
    if (i < nsel) {
        int k = selK[i];
        cellvox[k] = rank;
        int cx = k & 255, cy = (k >> 8) & 127, cz = k >> 15;
        out_coors[rank * 3 + 0] = (float)cz;        // coor_rev = [cz, cy, cx]
        out_coors[rank * 3 + 1] = (float)cy;
        out_coors[rank * 3 + 2] = (float)cx;
    }
}

__global__ void k_scatter(const float4* __restrict__ x, const int* __restrict__ meta,
                          const int* __restrict__ cellvox, int* __restrict__ cnt,
                          int* __restrict__ bucket) {
    int cutoff = meta[M_CUTOFF];
    int stride = gridDim.x * blockDim.x;
    for (int i = blockIdx.x * blockDim.x + threadIdx.x; i < cutoff; i += stride) {
        float4 p = x[i];
        bool valid; int key = point_key(p.x, p.y, p.z, valid);
        if (!valid) continue;
        int v = cellvox[key];                       // guaranteed set: first[key] <= i < cutoff
        int a = atomicAdd(&cnt[v], 1);
        if (a < KCAP) bucket[v * KCAP + a] = i;
    }
}

__global__ void k_fill(const float4* __restrict__ x, const int* __restrict__ meta,
                       const int* __restrict__ cnt, const int* __restrict__ bucket,
                       float* __restrict__ out_vox, float* __restrict__ out_num,
                       float* __restrict__ out_voxnum) {
    int v = blockIdx.x * blockDim.x + threadIdx.x;
    int nsel = meta[M_NSEL];
    if (v == 0) out_voxnum[0] = (float)nsel;
    if (v >= nsel) return;
    int count = cnt[v];
    int m   = count < KCAP ? count : KCAP;
    int npv = count < MAXP ? count : MAXP;
    out_num[v] = (float)npv;
    const int* b = &bucket[v * KCAP];
    for (int a = 0; a < m; ++a) {
        int e = b[a];
        int pos = 0;
        for (int q = 0; q < m; ++q) pos += (b[q] < e);  // slot = rank by point index
        if (pos < MAXP) {
            float4 p = x[e];
            *(float4*)(&out_vox[(size_t)(v * MAXP + pos) * 4]) = p;
        }
    }
}

extern "C" void kernel_launch(void* const* d_in, const int* in_sizes, int n_in,
                              void* d_out, int out_size, void* d_ws, size_t ws_size,
                              hipStream_t stream) {
    const float4* x = (const float4*)d_in[0];
    int n = in_sizes[0] / 4;
    float* out        = (float*)d_out;
    float* out_vox    = out;                         // 12000*100*4 = 4,800,000
    float* out_num    = out + 4800000;               // 12,000
    float* out_coors  = out + 4812000;               // 36,000
    float* out_voxnum = out + 4848000;               // 1

    int* w       = (int*)d_ws;
    int* first   = w;                 // 32768
    int* meta    = w + 32768;         // 64
    int* hist    = w + 32832;         // 1024
    int* cand    = w + 33856;         // 2048
    int* selF    = w + 35904;         // 12000
    int* selK    = w + 47904;         // 12000
    int* cellvox = w + 59904;         // 32768
    int* cnt     = w + 92672;         // 12000
    int* bucket  = w + 104672;        // 12000*128 = 1,536,000  (total ~6.6 MB)

    hipMemsetAsync(d_out, 0, (size_t)out_size * sizeof(float), stream);
    hipMemsetAsync(first, 0x7F, NCELLS * sizeof(int), stream);            // FINF pattern
    hipMemsetAsync(meta, 0, (64 + 1024) * sizeof(int), stream);           // meta + hist
    hipMemsetAsync(cnt, 0, MAXV * sizeof(int), stream);

    k_points <<<(n + 255) / 256, 256, 0, stream>>>(x, n, first);
    k_hist   <<<NCELLS / 256, 256, 0, stream>>>(first, hist);
    k_select <<<1, 1024, 0, stream>>>(hist, meta, n);
    k_cand   <<<NCELLS / 256, 256, 0, stream>>>(first, meta, cand);
    k_cut    <<<1, 256, 0, stream>>>(cand, meta);
    k_collect<<<NCELLS / 256, 256, 0, stream>>>(first, meta, selF, selK);
    k_rank   <<<(MAXV + 255) / 256, 256, 0, stream>>>(selF, selK, meta, cellvox, out_coors);
    k_scatter<<<512, 256, 0, stream>>>(x, meta, cellvox, cnt, bucket);
    k_fill   <<<(MAXV + 255) / 256, 256, 0, stream>>>(x, meta, cnt, bucket, out_vox, out_num, out_voxnum);
}

// Round 2
// 176.388 us; speedup vs baseline: 1.8690x; 1.8690x over previous
//
#include <hip/hip_runtime.h>

#define NCELLS 32768      // 256*128*1
#define MAXV   12000
#define MAXP   100
#define KCAP   128
#define FINF   0x7F7F7F7F // > any point index, works as +inf for atomicMin
#define BSHIFT 11
#define BMASK  ((1 << BSHIFT) - 1)

// meta slots
#define M_NSEL   0
#define M_CUTOFF 1
#define M_BSTAR  2
#define M_BASE   3
#define M_NEED   4
#define M_VOXNUM 5

__device__ __forceinline__ int point_key(float px, float py, float pz, bool& valid) {
    // exact IEEE f32 match to reference: floor((x - lo)/vs), lo=(0,-10.24,-3), vs=(0.16,0.16,4)
    float fx = floorf((px - 0.0f)    / 0.16f);
    float fy = floorf((py + 10.24f)  / 0.16f);
    float fz = floorf((pz + 3.0f)    / 4.0f);
    valid = (fx >= 0.0f) && (fx < 256.0f) &&
            (fy >= 0.0f) && (fy < 128.0f) &&
            (fz >= 0.0f) && (fz < 1.0f);
    if (!valid) return 0;
    int cx = (int)fx, cy = (int)fy, cz = (int)fz;
    return (cz * 128 + cy) * 256 + cx;
}

__global__ void k_points(const float4* __restrict__ x, int n, int* __restrict__ first) {
    int i = blockIdx.x * blockDim.x + threadIdx.x;
    if (i >= n) return;
    float4 p = x[i];
    bool valid; int key = point_key(p.x, p.y, p.z, valid);
    if (valid) atomicMin(&first[key], i);
}

__global__ void k_hist(const int* __restrict__ first, int* __restrict__ hist) {
    int k = blockIdx.x * blockDim.x + threadIdx.x;
    if (k >= NCELLS) return;
    int f = first[k];
    if (f != FINF) atomicAdd(&hist[f >> BSHIFT], 1);   // buckets of 2048 indices
}

__global__ void k_select(const int* __restrict__ hist, int* __restrict__ meta, int n) {
    __shared__ int s[1024];
    int t = threadIdx.x;
    int v = hist[t];
    s[t] = v;
    __syncthreads();
    for (int d = 1; d < 1024; d <<= 1) {           // inclusive Hillis-Steele scan
        int add = (t >= d) ? s[t - d] : 0;
        __syncthreads();
        s[t] += add;
        __syncthreads();
    }
    int total = s[1023];
    int incl  = s[t];
    int excl  = incl - v;
    if (t == 0) {
        if (total <= MAXV) { meta[M_CUTOFF] = n; meta[M_VOXNUM] = total; meta[M_NEED] = 0; }
        else               { meta[M_VOXNUM] = MAXV; meta[M_NEED] = 1; }
    }
    // 0-based target rank = MAXV (the 12001st smallest first)
    if (total > MAXV && excl <= MAXV && incl > MAXV) {
        meta[M_BSTAR] = t;
        meta[M_BASE]  = excl;
    }
}

// mark candidate offsets within the critical bucket (values distinct -> plain store)
__global__ void k_flag(const int* __restrict__ first, const int* __restrict__ meta,
                       int* __restrict__ flags) {
    if (meta[M_NEED] == 0) return;
    int k = blockIdx.x * blockDim.x + threadIdx.x;
    if (k >= NCELLS) return;
    int f = first[k];
    if (f != FINF && (f >> BSHIFT) == meta[M_BSTAR]) flags[f & BMASK] = 1;
}

// scan the 2048-entry bitmap, pick the candidate at the target rank -> cutoff
__global__ void k_cut(const int* __restrict__ flags, int* __restrict__ meta) {
    if (meta[M_NEED] == 0) return;
    __shared__ int s[1024];
    int t = threadIdx.x;
    int f0 = flags[2 * t], f1 = flags[2 * t + 1];
    int pair = f0 + f1;
    s[t] = pair;
    __syncthreads();
    for (int d = 1; d < 1024; d <<= 1) {
        int add = (t >= d) ? s[t - d] : 0;
        __syncthreads();
        s[t] += add;
        __syncthreads();
    }
    int incl = s[t], excl = incl - pair;
    int target = MAXV - meta[M_BASE];
    int base   = meta[M_BSTAR] << BSHIFT;
    if (f0 && excl == target)        meta[M_CUTOFF] = base | (2 * t);
    if (f1 && (excl + f0) == target) meta[M_CUTOFF] = base | (2 * t + 1);
}

__global__ void k_collect(const int* __restrict__ first, int* __restrict__ meta,
                          int* __restrict__ selF, int* __restrict__ selK) {
    int k = blockIdx.x * blockDim.x + threadIdx.x;
    if (k >= NCELLS) return;
    int cutoff = meta[M_CUTOFF];
    int f = first[k];
    if (f < cutoff) {                               // FINF > n >= cutoff, excludes empty cells
        int pos = atomicAdd(&meta[M_NSEL], 1);
        selF[pos] = f;
        selK[pos] = k;
    }
}

// 2D-tiled pairwise ranking: block (bi, split) counts selF[j-tiles = split, split+16, ...] < selF[i]
#define NSPLIT 16
__global__ void k_rank_pairs(const int* __restrict__ selF, const int* __restrict__ meta,
                             int* __restrict__ rank) {
    int nsel = meta[M_NSEL];
    int bi = blockIdx.x;
    if (bi * 256 >= nsel) return;
    int split = blockIdx.y;
    int i = bi * 256 + threadIdx.x;
    int myF = (i < nsel) ? selF[i] : 0x7FFFFFFF;
    int cnt = 0;
    __shared__ int sf[256];
    for (int jt = split; jt * 256 < nsel; jt += NSPLIT) {
        int j = jt * 256 + (int)threadIdx.x;
        sf[threadIdx.x] = (j < nsel) ? selF[j] : 0x7FFFFFFF;
        __syncthreads();
        int lim = min(256, nsel - jt * 256);
        #pragma unroll 8
        for (int t = 0; t < lim; ++t) cnt += (sf[t] < myF);
        __syncthreads();
    }
    if (i < nsel && cnt) atomicAdd(&rank[i], cnt);
}

__global__ void k_rank_write(const int* __restrict__ selK, const int* __restrict__ rank,
                             const int* __restrict__ meta, int* __restrict__ cellvox,
                             float* __restrict__ out_coors) {
    int nsel = meta[M_NSEL];
    int i = blockIdx.x * blockDim.x + threadIdx.x;
    if (i >= nsel) return;
    int r = rank[i];
    int k = selK[i];
    cellvox[k] = r;
    int cx = k & 255, cy = (k >> 8) & 127, cz = k >> 15;
    out_coors[r * 3 + 0] = (float)cz;               // coor_rev = [cz, cy, cx]
    out_coors[r * 3 + 1] = (float)cy;
    out_coors[r * 3 + 2] = (float)cx;
}

__global__ void k_scatter(const float4* __restrict__ x, const int* __restrict__ meta,
                          const int* __restrict__ cellvox, int* __restrict__ cnt,
                          int* __restrict__ bucket) {
    int cutoff = meta[M_CUTOFF];
    int stride = gridDim.x * blockDim.x;
    for (int i = blockIdx.x * blockDim.x + threadIdx.x; i < cutoff; i += stride) {
        float4 p = x[i];
        bool valid; int key = point_key(p.x, p.y, p.z, valid);
        if (!valid) continue;
        int v = cellvox[key];                       // guaranteed set: first[key] <= i < cutoff
        int a = atomicAdd(&cnt[v], 1);
        if (a < KCAP) bucket[v * KCAP + a] = i;
    }
}

__global__ void k_fill(const float4* __restrict__ x, const int* __restrict__ meta,
                       const int* __restrict__ cnt, const int* __restrict__ bucket,
                       float* __restrict__ out_vox, float* __restrict__ out_num,
                       float* __restrict__ out_voxnum) {
    int v = blockIdx.x * blockDim.x + threadIdx.x;
    int nsel = meta[M_NSEL];
    if (v == 0) out_voxnum[0] = (float)nsel;
    if (v >= nsel) return;
    int count = cnt[v];
    int m   = count < KCAP ? count : KCAP;
    int npv = count < MAXP ? count : MAXP;
    out_num[v] = (float)npv;
    const int* b = &bucket[v * KCAP];
    for (int a = 0; a < m; ++a) {
        int e = b[a];
        int pos = 0;
        for (int q = 0; q < m; ++q) pos += (b[q] < e);  // slot = rank by point index
        if (pos < MAXP) {
            float4 p = x[e];
            *(float4*)(&out_vox[(size_t)(v * MAXP + pos) * 4]) = p;
        }
    }
}

extern "C" void kernel_launch(void* const* d_in, const int* in_sizes, int n_in,
                              void* d_out, int out_size, void* d_ws, size_t ws_size,
                              hipStream_t stream) {
    const float4* x = (const float4*)d_in[0];
    int n = in_sizes[0] / 4;
    float* out        = (float*)d_out;
    float* out_vox    = out;                         // 12000*100*4 = 4,800,000
    float* out_num    = out + 4800000;               // 12,000
    float* out_coors  = out + 4812000;               // 36,000
    float* out_voxnum = out + 4848000;               // 1

    int* w       = (int*)d_ws;
    int* first   = w;                  // 32768   (memset 0x7F)
    // ---- contiguous zero region start ----
    int* meta    = w + 32768;          // 64
    int* hist    = w + 32832;          // 1024
    int* flags   = w + 33856;          // 2048
    int* rank    = w + 35904;          // 12032
    int* cnt     = w + 47936;          // 12032
    // ---- contiguous zero region end (27200 ints) ----
    int* selF    = w + 59968;          // 12032
    int* selK    = w + 72000;          // 12032
    int* cellvox = w + 84032;          // 32768
    int* bucket  = w + 116800;         // 12000*128 = 1,536,000  (total ~6.6 MB)

    hipMemsetAsync(d_out, 0, (size_t)out_size * sizeof(float), stream);
    hipMemsetAsync(first, 0x7F, NCELLS * sizeof(int), stream);            // FINF pattern
    hipMemsetAsync(meta, 0, 27200 * sizeof(int), stream);                 // meta..cnt

    k_points    <<<(n + 255) / 256, 256, 0, stream>>>(x, n, first);
    k_hist      <<<NCELLS / 256, 256, 0, stream>>>(first, hist);
    k_select    <<<1, 1024, 0, stream>>>(hist, meta, n);
    k_flag      <<<NCELLS / 256, 256, 0, stream>>>(first, meta, flags);
    k_cut       <<<1, 1024, 0, stream>>>(flags, meta);
    k_collect   <<<NCELLS / 256, 256, 0, stream>>>(first, meta, selF, selK);
    k_rank_pairs<<<dim3((MAXV + 255) / 256, NSPLIT), 256, 0, stream>>>(selF, meta, rank);
    k_rank_write<<<(MAXV + 255) / 256, 256, 0, stream>>>(selK, rank, meta, cellvox, out_coors);
    k_scatter   <<<512, 256, 0, stream>>>(x, meta, cellvox, cnt, bucket);
    k_fill      <<<(MAXV + 255) / 256, 256, 0, stream>>>(x, meta, cnt, bucket, out_vox, out_num, out_voxnum);
}

// Round 3
// 71.807 us; speedup vs baseline: 4.5910x; 2.4564x over previous
//
#include <hip/hip_runtime.h>

#define NCELLS   32768      // 256*128*1
#define MAXV     12000
#define MAXP     100
#define KCAP     128
#define FINF     0x7F7F7F7F // > any point index, works as +inf for atomicMin
#define P_PREFIX 131072
#define BITWORDS 63488      // 1024 threads * 62 words; covers 2M point indices

// meta slots
#define M_NSEL   0
#define M_CUTOFF 1
#define M_PRETOT 2

__device__ __forceinline__ int point_key(float px, float py, float pz, bool& valid) {
    // exact IEEE f32 match to reference: floor((x - lo)/vs), lo=(0,-10.24,-3), vs=(0.16,0.16,4)
    float fx = floorf((px - 0.0f)    / 0.16f);
    float fy = floorf((py + 10.24f)  / 0.16f);
    float fz = floorf((pz + 3.0f)    / 4.0f);
    valid = (fx >= 0.0f) && (fx < 256.0f) &&
            (fy >= 0.0f) && (fy < 128.0f) &&
            (fz >= 0.0f) && (fz < 1.0f);
    if (!valid) return 0;
    int cx = (int)fx, cy = (int)fy, cz = (int)fz;
    return (cz * 128 + cy) * 256 + cx;
}

// read-check before atomicMin: first[] is monotone decreasing, so a read <= i
// proves the true min <= i and the atomic would be a no-op -> skip safely.
__global__ void k_points_prefix(const float4* __restrict__ x, int pn, int* __restrict__ first) {
    int i = blockIdx.x * blockDim.x + threadIdx.x;
    if (i >= pn) return;
    float4 p = x[i];
    bool valid; int key = point_key(p.x, p.y, p.z, valid);
    if (!valid) return;
    if (first[key] > i) atomicMin(&first[key], i);
}

// count distinct cells found in prefix (one atomic per 1024-block)
__global__ void k_check(const int* __restrict__ first, int* __restrict__ meta) {
    __shared__ int wc[16];
    int k = blockIdx.x * 1024 + threadIdx.x;
    int occ = (first[k] != FINF) ? 1 : 0;
    unsigned long long m = __ballot(occ);
    int lane = threadIdx.x & 63;
    int w = threadIdx.x >> 6;
    if (lane == 0) wc[w] = __popcll(m);
    __syncthreads();
    if (threadIdx.x == 0) {
        int tot = 0;
        for (int i = 0; i < 16; ++i) tot += wc[i];
        atomicAdd(&meta[M_PRETOT], tot);
    }
}

// fallback: only runs the remaining points if the prefix didn't already
// produce > MAXV distinct cells (then cutoff < P_PREFIX and they can't matter)
__global__ void k_points_rest(const float4* __restrict__ x, int pn, int n,
                              const int* __restrict__ meta, int* __restrict__ first) {
    if (meta[M_PRETOT] > MAXV) return;
    int stride = gridDim.x * blockDim.x;
    for (int i = pn + blockIdx.x * blockDim.x + threadIdx.x; i < n; i += stride) {
        float4 p = x[i];
        bool valid; int key = point_key(p.x, p.y, p.z, valid);
        if (!valid) continue;
        if (first[key] > i) atomicMin(&first[key], i);
    }
}

// first-occurrence indices are distinct across cells -> set bits in a bitmap
__global__ void k_bitmap(const int* __restrict__ first, unsigned* __restrict__ bitmap) {
    int k = blockIdx.x * blockDim.x + threadIdx.x;
    if (k >= NCELLS) return;
    int f = first[k];
    if (f != FINF) atomicOr(&bitmap[f >> 5], 1u << (f & 31));
}

// popcount+scan the bitmap; the rank-MAXV (0-based) set bit IS the cutoff index
__global__ void k_cut2(const unsigned* __restrict__ bitmap, int* __restrict__ meta, int n) {
    __shared__ int s[1024];
    int t = threadIdx.x;
    int base = t * 62;
    int mysum = 0;
    #pragma unroll
    for (int j = 0; j < 62; ++j) mysum += __popc(bitmap[base + j]);
    s[t] = mysum;
    __syncthreads();
    for (int d = 1; d < 1024; d <<= 1) {
        int add = (t >= d) ? s[t - d] : 0;
        __syncthreads();
        s[t] += add;
        __syncthreads();
    }
    int total = s[1023];
    int incl = s[t], excl = incl - mysum;
    if (t == 0 && total <= MAXV) meta[M_CUTOFF] = n;
    if (total > MAXV && excl <= MAXV && incl > MAXV) {
        int target = MAXV - excl;              // 0-based rank within my chunk
        int acc = 0;
        for (int j = 0; j < 62; ++j) {
            unsigned wv = bitmap[base + j];
            int pc = __popc(wv);
            if (acc + pc > target) {
                unsigned xv = wv;
                for (int b = target - acc; b > 0; --b) xv &= xv - 1;  // drop lowest bits
                meta[M_CUTOFF] = (base + j) * 32 + (__ffs(xv) - 1);
                break;
            }
            acc += pc;
        }
    }
}

// compact selected cells; one global atomic per block, ballot-prefix within
__global__ void k_collect(const int* __restrict__ first, int* __restrict__ meta,
                          int* __restrict__ selF, int* __restrict__ selK) {
    __shared__ int wcnt[16];
    __shared__ int wbase[16];
    int k = blockIdx.x * 1024 + threadIdx.x;
    int cutoff = meta[M_CUTOFF];
    int f = first[k];
    int pred = (f < cutoff) ? 1 : 0;           // FINF > n >= cutoff excludes empty cells
    unsigned long long m = __ballot(pred);
    int lane = threadIdx.x & 63;
    int w = threadIdx.x >> 6;
    if (lane == 0) wcnt[w] = __popcll(m);
    __syncthreads();
    if (threadIdx.x == 0) {
        int tot = 0, off[16];
        for (int i = 0; i < 16; ++i) { off[i] = tot; tot += wcnt[i]; }
        int b = atomicAdd(&meta[M_NSEL], tot);
        for (int i = 0; i < 16; ++i) wbase[i] = b + off[i];
    }
    __syncthreads();
    if (pred) {
        int pos = wbase[w] + __popcll(m & ((1ull << lane) - 1));
        selF[pos] = f;
        selK[pos] = k;
    }
}

// 2D-tiled pairwise ranking: block (bi, split) counts selF[j in tiles split::16] < selF[i]
#define NSPLIT 16
__global__ void k_rank_pairs(const int* __restrict__ selF, const int* __restrict__ meta,
                             int* __restrict__ rank) {
    int nsel = meta[M_NSEL];
    int bi = blockIdx.x;
    if (bi * 256 >= nsel) return;
    int split = blockIdx.y;
    int i = bi * 256 + threadIdx.x;
    int myF = (i < nsel) ? selF[i] : 0x7FFFFFFF;
    int cnt = 0;
    __shared__ int sf[256];
    for (int jt = split; jt * 256 < nsel; jt += NSPLIT) {
        int j = jt * 256 + (int)threadIdx.x;
        sf[threadIdx.x] = (j < nsel) ? selF[j] : 0x7FFFFFFF;
        __syncthreads();
        int lim = min(256, nsel - jt * 256);
        #pragma unroll 8
        for (int t = 0; t < lim; ++t) cnt += (sf[t] < myF);
        __syncthreads();
    }
    if (i < nsel && cnt) atomicAdd(&rank[i], cnt);
}

__global__ void k_rank_write(const int* __restrict__ selK, const int* __restrict__ rank,
                             const int* __restrict__ meta, int* __restrict__ cellvox,
                             float* __restrict__ out_coors) {
    int nsel = meta[M_NSEL];
    int i = blockIdx.x * blockDim.x + threadIdx.x;
    if (i >= nsel) return;
    int r = rank[i];
    int k = selK[i];
    cellvox[k] = r;
    int cx = k & 255, cy = (k >> 8) & 127, cz = k >> 15;
    out_coors[r * 3 + 0] = (float)cz;               // coor_rev = [cz, cy, cx]
    out_coors[r * 3 + 1] = (float)cy;
    out_coors[r * 3 + 2] = (float)cx;
}

__global__ void k_scatter(const float4* __restrict__ x, const int* __restrict__ meta,
                          const int* __restrict__ cellvox, int* __restrict__ cnt,
                          int* __restrict__ bucket) {
    int cutoff = meta[M_CUTOFF];
    int stride = gridDim.x * blockDim.x;
    for (int i = blockIdx.x * blockDim.x + threadIdx.x; i < cutoff; i += stride) {
        float4 p = x[i];
        bool valid; int key = point_key(p.x, p.y, p.z, valid);
        if (!valid) continue;
        int v = cellvox[key];                       // guaranteed set: first[key] <= i < cutoff
        int a = atomicAdd(&cnt[v], 1);
        if (a < KCAP) bucket[v * KCAP + a] = i;
    }
}

__global__ void k_fill(const float4* __restrict__ x, const int* __restrict__ meta,
                       const int* __restrict__ cnt, const int* __restrict__ bucket,
                       float* __restrict__ out_vox, float* __restrict__ out_num,
                       float* __restrict__ out_voxnum) {
    int v = blockIdx.x * blockDim.x + threadIdx.x;
    int nsel = meta[M_NSEL];
    if (v == 0) out_voxnum[0] = (float)nsel;
    if (v >= nsel) return;
    int count = cnt[v];
    int m   = count < KCAP ? count : KCAP;
    int npv = count < MAXP ? count : MAXP;
    out_num[v] = (float)npv;
    const int* b = &bucket[v * KCAP];
    for (int a = 0; a < m; ++a) {
        int e = b[a];
        int pos = 0;
        for (int q = 0; q < m; ++q) pos += (b[q] < e);  // slot = rank by point index
        if (pos < MAXP) {
            float4 p = x[e];
            *(float4*)(&out_vox[(size_t)(v * MAXP + pos) * 4]) = p;
        }
    }
}

extern "C" void kernel_launch(void* const* d_in, const int* in_sizes, int n_in,
                              void* d_out, int out_size, void* d_ws, size_t ws_size,
                              hipStream_t stream) {
    const float4* x = (const float4*)d_in[0];
    int n = in_sizes[0] / 4;
    int pn = n < P_PREFIX ? n : P_PREFIX;
    float* out        = (float*)d_out;
    float* out_vox    = out;                         // 12000*100*4 = 4,800,000
    float* out_num    = out + 4800000;               // 12,000
    float* out_coors  = out + 4812000;               // 36,000
    float* out_voxnum = out + 4848000;               // 1

    int* w = (int*)d_ws;
    // ---- zero region: meta, rank, cnt, bitmap(=bucket head) ----
    int*      meta    = w;                 // 64
    int*      rank    = w + 64;            // 12032
    int*      cnt     = w + 12096;         // 12032
    int*      bucket  = w + 24128;         // 12000*128 = 1,536,000
    unsigned* bitmap  = (unsigned*)bucket; // aliased: bitmap (63488) consumed before bucket written
    int*      first   = w + 1560128;       // 32768 (memset 0x7F)
    int*      selF    = w + 1592896;       // 12032
    int*      selK    = w + 1604928;       // 12032
    int*      cellvox = w + 1616960;       // 32768  -> end 1,649,728 ints (~6.6 MB)

    hipMemsetAsync(d_out, 0, (size_t)out_size * sizeof(float), stream);
    hipMemsetAsync(w, 0, (24128 + BITWORDS) * sizeof(int), stream);   // meta..cnt + bitmap
    hipMemsetAsync(first, 0x7F, NCELLS * sizeof(int), stream);        // FINF pattern

    k_points_prefix<<<(pn + 255) / 256, 256, 0, stream>>>(x, pn, first);
    k_check        <<<NCELLS / 1024, 1024, 0, stream>>>(first, meta);
    if (n > pn)
        k_points_rest<<<256, 1024, 0, stream>>>(x, pn, n, meta, first);
    k_bitmap       <<<NCELLS / 256, 256, 0, stream>>>(first, bitmap);
    k_cut2         <<<1, 1024, 0, stream>>>(bitmap, meta, n);
    k_collect      <<<NCELLS / 1024, 1024, 0, stream>>>(first, meta, selF, selK);
    k_rank_pairs   <<<dim3((MAXV + 255) / 256, NSPLIT), 256, 0, stream>>>(selF, meta, rank);
    k_rank_write   <<<(MAXV + 255) / 256, 256, 0, stream>>>(selK, rank, meta, cellvox, out_coors);
    k_scatter      <<<256, 256, 0, stream>>>(x, meta, cellvox, cnt, bucket);
    k_fill         <<<(MAXV + 255) / 256, 256, 0, stream>>>(x, meta, cnt, bucket, out_vox, out_num, out_voxnum);
}

// Round 4
// 68.487 us; speedup vs baseline: 4.8136x; 1.0485x over previous
//
#include <hip/hip_runtime.h>

#define NCELLS   32768      // 256*128*1
#define MAXV     12000
#define MAXP     100
#define KCAP     128
#define FINF     0x7F7F7F7F // > any point index, works as +inf for atomicMin
#define P_PREFIX 131072
#define BITWORDS 63488      // 1024 threads * 62 words; covers 2M point indices

// meta slots
#define M_NSEL   0
#define M_CUTOFF 1
#define M_PRETOT 2

__device__ __forceinline__ int point_key(float px, float py, float pz, bool& valid) {
    // exact IEEE f32 match to reference: floor((x - lo)/vs), lo=(0,-10.24,-3), vs=(0.16,0.16,4)
    float fx = floorf((px - 0.0f)    / 0.16f);
    float fy = floorf((py + 10.24f)  / 0.16f);
    float fz = floorf((pz + 3.0f)    / 4.0f);
    valid = (fx >= 0.0f) && (fx < 256.0f) &&
            (fy >= 0.0f) && (fy < 128.0f) &&
            (fz >= 0.0f) && (fz < 1.0f);
    if (!valid) return 0;
    int cx = (int)fx, cy = (int)fy, cz = (int)fz;
    return (cz * 128 + cy) * 256 + cx;
}

// workspace init: zeros for meta/rank/cnt/bitmap (contiguous), FINF pattern for first
#define ZINT4 21904   // (64 + 12032 + 12032 + 63488) / 4
#define FINT4 8192    // 32768 / 4
__global__ void k_init(int4* __restrict__ wz, int4* __restrict__ first4) {
    int i = blockIdx.x * blockDim.x + threadIdx.x;
    if (i < ZINT4) wz[i] = make_int4(0, 0, 0, 0);
    int j = i - ZINT4;
    if (j >= 0 && j < FINT4) first4[j] = make_int4(FINF, FINF, FINF, FINF);
}

// read-check before atomicMin: first[] is monotone decreasing, so a read <= i
// proves the true min <= i and the atomic would be a no-op -> skip safely.
__global__ void k_points_prefix(const float4* __restrict__ x, int pn, int* __restrict__ first) {
    int i = blockIdx.x * blockDim.x + threadIdx.x;
    if (i >= pn) return;
    float4 p = x[i];
    bool valid; int key = point_key(p.x, p.y, p.z, valid);
    if (!valid) return;
    if (first[key] > i) atomicMin(&first[key], i);
}

// count distinct cells found in prefix (one atomic per 1024-block)
__global__ void k_check(const int* __restrict__ first, int* __restrict__ meta) {
    __shared__ int wc[16];
    int k = blockIdx.x * 1024 + threadIdx.x;
    int occ = (first[k] != FINF) ? 1 : 0;
    unsigned long long m = __ballot(occ);
    int lane = threadIdx.x & 63;
    int w = threadIdx.x >> 6;
    if (lane == 0) wc[w] = __popcll(m);
    __syncthreads();
    if (threadIdx.x == 0) {
        int tot = 0;
        for (int i = 0; i < 16; ++i) tot += wc[i];
        atomicAdd(&meta[M_PRETOT], tot);
    }
}

// fallback: only runs the remaining points if the prefix didn't already
// produce > MAXV distinct cells (then cutoff < P_PREFIX and they can't matter)
__global__ void k_points_rest(const float4* __restrict__ x, int pn, int n,
                              const int* __restrict__ meta, int* __restrict__ first) {
    if (meta[M_PRETOT] > MAXV) return;
    int stride = gridDim.x * blockDim.x;
    for (int i = pn + blockIdx.x * blockDim.x + threadIdx.x; i < n; i += stride) {
        float4 p = x[i];
        bool valid; int key = point_key(p.x, p.y, p.z, valid);
        if (!valid) continue;
        if (first[key] > i) atomicMin(&first[key], i);
    }
}

// first-occurrence indices are distinct across cells -> set bits in a bitmap
__global__ void k_bitmap(const int* __restrict__ first, unsigned* __restrict__ bitmap) {
    int k = blockIdx.x * blockDim.x + threadIdx.x;
    if (k >= NCELLS) return;
    int f = first[k];
    if (f != FINF) atomicOr(&bitmap[f >> 5], 1u << (f & 31));
}

// popcount+scan the bitmap; the rank-MAXV (0-based) set bit IS the cutoff index
__global__ void k_cut2(const unsigned* __restrict__ bitmap, int* __restrict__ meta, int n) {
    __shared__ int s[1024];
    int t = threadIdx.x;
    int base = t * 62;
    int mysum = 0;
    #pragma unroll
    for (int j = 0; j < 62; ++j) mysum += __popc(bitmap[base + j]);
    s[t] = mysum;
    __syncthreads();
    for (int d = 1; d < 1024; d <<= 1) {
        int add = (t >= d) ? s[t - d] : 0;
        __syncthreads();
        s[t] += add;
        __syncthreads();
    }
    int total = s[1023];
    int incl = s[t], excl = incl - mysum;
    if (t == 0 && total <= MAXV) meta[M_CUTOFF] = n;
    if (total > MAXV && excl <= MAXV && incl > MAXV) {
        int target = MAXV - excl;              // 0-based rank within my chunk
        int acc = 0;
        for (int j = 0; j < 62; ++j) {
            unsigned wv = bitmap[base + j];
            int pc = __popc(wv);
            if (acc + pc > target) {
                unsigned xv = wv;
                for (int b = target - acc; b > 0; --b) xv &= xv - 1;  // drop lowest bits
                meta[M_CUTOFF] = (base + j) * 32 + (__ffs(xv) - 1);
                break;
            }
            acc += pc;
        }
    }
}

// compact selected cells; one global atomic per block, ballot-prefix within
__global__ void k_collect(const int* __restrict__ first, int* __restrict__ meta,
                          int* __restrict__ selF, int* __restrict__ selK) {
    __shared__ int wcnt[16];
    __shared__ int wbase[16];
    int k = blockIdx.x * 1024 + threadIdx.x;
    int cutoff = meta[M_CUTOFF];
    int f = first[k];
    int pred = (f < cutoff) ? 1 : 0;           // FINF > n >= cutoff excludes empty cells
    unsigned long long m = __ballot(pred);
    int lane = threadIdx.x & 63;
    int w = threadIdx.x >> 6;
    if (lane == 0) wcnt[w] = __popcll(m);
    __syncthreads();
    if (threadIdx.x == 0) {
        int tot = 0, off[16];
        for (int i = 0; i < 16; ++i) { off[i] = tot; tot += wcnt[i]; }
        int b = atomicAdd(&meta[M_NSEL], tot);
        for (int i = 0; i < 16; ++i) wbase[i] = b + off[i];
    }
    __syncthreads();
    if (pred) {
        int pos = wbase[w] + __popcll(m & ((1ull << lane) - 1));
        selF[pos] = f;
        selK[pos] = k;
    }
}

// 2D-tiled pairwise ranking: block (bi, split) counts selF[j in tiles split::16] < selF[i]
#define NSPLIT 16
__global__ void k_rank_pairs(const int* __restrict__ selF, const int* __restrict__ meta,
                             int* __restrict__ rank) {
    int nsel = meta[M_NSEL];
    int bi = blockIdx.x;
    if (bi * 256 >= nsel) return;
    int split = blockIdx.y;
    int i = bi * 256 + threadIdx.x;
    int myF = (i < nsel) ? selF[i] : 0x7FFFFFFF;
    int cnt = 0;
    __shared__ int sf[256];
    for (int jt = split; jt * 256 < nsel; jt += NSPLIT) {
        int j = jt * 256 + (int)threadIdx.x;
        sf[threadIdx.x] = (j < nsel) ? selF[j] : 0x7FFFFFFF;
        __syncthreads();
        int lim = min(256, nsel - jt * 256);
        #pragma unroll 8
        for (int t = 0; t < lim; ++t) cnt += (sf[t] < myF);
        __syncthreads();
    }
    if (i < nsel && cnt) atomicAdd(&rank[i], cnt);
}

__global__ void k_rank_write(const int* __restrict__ selK, const int* __restrict__ rank,
                             const int* __restrict__ meta, int* __restrict__ cellvox,
                             float* __restrict__ out_coors) {
    int nsel = meta[M_NSEL];
    int i = blockIdx.x * blockDim.x + threadIdx.x;
    if (i >= nsel) return;
    int r = rank[i];
    int k = selK[i];
    cellvox[k] = r;
    int cx = k & 255, cy = (k >> 8) & 127, cz = k >> 15;
    out_coors[r * 3 + 0] = (float)cz;               // coor_rev = [cz, cy, cx]
    out_coors[r * 3 + 1] = (float)cy;
    out_coors[r * 3 + 2] = (float)cx;
}

__global__ void k_scatter(const float4* __restrict__ x, const int* __restrict__ meta,
                          const int* __restrict__ cellvox, int* __restrict__ cnt,
                          int* __restrict__ bucket) {
    int cutoff = meta[M_CUTOFF];
    int stride = gridDim.x * blockDim.x;
    for (int i = blockIdx.x * blockDim.x + threadIdx.x; i < cutoff; i += stride) {
        float4 p = x[i];
        bool valid; int key = point_key(p.x, p.y, p.z, valid);
        if (!valid) continue;
        int v = cellvox[key];                       // guaranteed set: first[key] <= i < cutoff
        int a = atomicAdd(&cnt[v], 1);
        if (a < KCAP) bucket[v * KCAP + a] = i;
    }
}

// wave-per-voxel epilogue: writes EVERY byte of out_vox (filled slots from
// bucket index-ranking, rest zeros), out_num for all v, coors rows >= nsel,
// and voxel_num. Replaces the 19.4 MB d_out memset entirely.
__global__ void __launch_bounds__(256)
k_fill(const float4* __restrict__ x, const int* __restrict__ meta,
       const int* __restrict__ cnt, const int* __restrict__ bucket,
       float4* __restrict__ out_vox, float* __restrict__ out_num,
       float* __restrict__ out_coors, float* __restrict__ out_voxnum) {
    __shared__ int sp[4][MAXP];
    int wid  = threadIdx.x >> 6;
    int lane = threadIdx.x & 63;
    int v = blockIdx.x * 4 + wid;                  // grid is exactly MAXV/4 blocks
    int nsel = meta[M_NSEL];
    int* slot_point = sp[wid];
    for (int s = lane; s < MAXP; s += 64) slot_point[s] = -1;
    if (v == 0 && lane == 0) out_voxnum[0] = (float)nsel;
    if (v < nsel) {
        if (lane == 0) {
            int count = cnt[v];
            out_num[v] = (float)(count < MAXP ? count : MAXP);
        }
        int count = cnt[v];
        int m = count < KCAP ? count : KCAP;
        const int* b = &bucket[v * KCAP];
        for (int a = lane; a < m; a += 64) {
            int e = b[a];
            int pos = 0;
            for (int q = 0; q < m; ++q) pos += (b[q] < e);  // slot = rank by point index
            if (pos < MAXP) slot_point[pos] = e;
        }
    } else {
        if (lane == 0) out_num[v] = 0.0f;
        if (lane < 3) out_coors[v * 3 + lane] = 0.0f;       // disjoint from k_rank_write rows
    }
    __syncthreads();
    float4 z = make_float4(0.f, 0.f, 0.f, 0.f);
    for (int s = lane; s < MAXP; s += 64) {
        int e = slot_point[s];
        out_vox[(size_t)v * MAXP + s] = (e >= 0) ? x[e] : z;
    }
}

extern "C" void kernel_launch(void* const* d_in, const int* in_sizes, int n_in,
                              void* d_out, int out_size, void* d_ws, size_t ws_size,
                              hipStream_t stream) {
    const float4* x = (const float4*)d_in[0];
    int n = in_sizes[0] / 4;
    int pn = n < P_PREFIX ? n : P_PREFIX;
    float* out        = (float*)d_out;
    float4* out_vox   = (float4*)out;                // 12000*100 float4s
    float* out_num    = out + 4800000;               // 12,000
    float* out_coors  = out + 4812000;               // 36,000
    float* out_voxnum = out + 4848000;               // 1

    int* w = (int*)d_ws;
    // ---- contiguous zero region: meta, rank, cnt, bitmap(=bucket head) ----
    int*      meta    = w;                 // 64
    int*      rank    = w + 64;            // 12032
    int*      cnt     = w + 12096;         // 12032
    int*      bucket  = w + 24128;         // 12000*128 = 1,536,000
    unsigned* bitmap  = (unsigned*)bucket; // aliased: bitmap consumed before bucket written
    int*      first   = w + 1560128;       // 32768 (FINF pattern)
    int*      selF    = w + 1592896;       // 12032
    int*      selK    = w + 1604928;       // 12032
    int*      cellvox = w + 1616960;       // 32768  -> end 1,649,728 ints (~6.6 MB)

    k_init         <<<(ZINT4 + FINT4 + 255) / 256, 256, 0, stream>>>((int4*)w, (int4*)first);
    k_points_prefix<<<(pn + 255) / 256, 256, 0, stream>>>(x, pn, first);
    k_check        <<<NCELLS / 1024, 1024, 0, stream>>>(first, meta);
    if (n > pn)
        k_points_rest<<<256, 1024, 0, stream>>>(x, pn, n, meta, first);
    k_bitmap       <<<NCELLS / 256, 256, 0, stream>>>(first, bitmap);
    k_cut2         <<<1, 1024, 0, stream>>>(bitmap, meta, n);
    k_collect      <<<NCELLS / 1024, 1024, 0, stream>>>(first, meta, selF, selK);
    k_rank_pairs   <<<dim3((MAXV + 255) / 256, NSPLIT), 256, 0, stream>>>(selF, meta, rank);
    k_rank_write   <<<(MAXV + 255) / 256, 256, 0, stream>>>(selK, rank, meta, cellvox, out_coors);
    k_scatter      <<<256, 256, 0, stream>>>(x, meta, cellvox, cnt, bucket);
    k_fill         <<<MAXV / 4, 256, 0, stream>>>(x, meta, cnt, bucket,
                                                  out_vox, out_num, out_coors, out_voxnum);
}